// Round 2
// baseline (59.548 us; speedup 1.0000x reference)
//
#include <hip/hip_runtime.h>

#define NCELLS (16384 * 7 * 7)   // 802816
#define CPB 256                  // cells per block
#define NBLOCKS (NCELLS / CPB)   // 3136, exact
#define INV_BATCH (1.0f / 16384.0f)
#define EPS 1e-12f
#define IMG 448.0f
#define CELL (448.0f / 7.0f)     // 64
#define L_COORD 5.0f
#define L_NOOBJ 0.5f

__device__ __forceinline__ float iou_f(const float* bp, const float* bt) {
    float cxp = bp[0] * CELL, cyp = bp[1] * CELL;
    float wp  = bp[2] * IMG,  hp  = bp[3] * IMG;
    float cxt = bt[0] * CELL, cyt = bt[1] * CELL;
    float wt  = bt[2] * IMG,  ht  = bt[3] * IMG;
    float iw = fmaxf(fminf(cxp + wp * 0.5f, cxt + wt * 0.5f) -
                     fmaxf(cxp - wp * 0.5f, cxt - wt * 0.5f), 0.0f);
    float ih = fmaxf(fminf(cyp + hp * 0.5f, cyt + ht * 0.5f) -
                     fmaxf(cyp - hp * 0.5f, cyt - ht * 0.5f), 0.0f);
    float inter = iw * ih;
    float uni = wp * hp + wt * ht - inter;
    return inter / (uni + EPS);
}

__device__ __forceinline__ float coord_loss(const float* bp, const float* tb) {
    float xy = (bp[0] - tb[0]) * (bp[0] - tb[0]) + (bp[1] - tb[1]) * (bp[1] - tb[1]);
    float s2 = sqrtf(bp[2] + EPS) - sqrtf(tb[2] + EPS);
    float s3 = sqrtf(bp[3] + EPS) - sqrtf(tb[3] + EPS);
    return xy + s2 * s2 + s3 * s3;
}

__global__ void __launch_bounds__(256) yolo_loss_kernel(
        const float* __restrict__ y_pre,
        const float* __restrict__ y_true,
        float* __restrict__ out) {
    // ---- stage this block's y_pre chunk (256 cells x 30 floats) via LDS ----
    __shared__ float4 sp4[CPB * 30 / 4];             // 1920 float4 = 30720 B
    float* sp = reinterpret_cast<float*>(sp4);

    const int tid = threadIdx.x;
    const size_t base4 = (size_t)blockIdx.x * (CPB * 30 / 4);
    const float4* g4 = reinterpret_cast<const float4*>(y_pre) + base4;

    #pragma unroll
    for (int i = 0; i < 8; ++i) {
        int idx = tid + i * 256;
        if (idx < CPB * 30 / 4) sp4[idx] = g4[idx];  // coalesced 16B, dense lines
    }
    __syncthreads();

    // ---- per-thread cell compute ----
    const int cell = blockIdx.x * CPB + tid;

    // y_true: 8 floats, 32B-aligned, line-dense without staging
    float tv[8];
    {
        const float4* t4 = reinterpret_cast<const float4*>(y_true) + (size_t)cell * 2;
        float4 ta = t4[0], tb4 = t4[1];
        tv[0] = ta.x; tv[1] = ta.y; tv[2] = ta.z; tv[3] = ta.w;
        tv[4] = tb4.x; tv[5] = tb4.y; tv[6] = tb4.z; tv[7] = tb4.w;
    }

    // y_pre: 30 floats from LDS (8B-aligned -> float2 reads)
    float pv[30];
    {
        const float2* l2 = reinterpret_cast<const float2*>(sp + tid * 30);
        #pragma unroll
        for (int i = 0; i < 15; ++i) {
            float2 v = l2[i];
            pv[2 * i]     = v.x;
            pv[2 * i + 1] = v.y;
        }
    }

    float c1 = pv[4], c2 = pv[9];
    bool obj = (tv[0] != 0.0f);
    float loss;
    if (obj) {
        const float* tbx = tv + 1;
        float iou1 = iou_f(pv + 0, tbx);
        float iou2 = iou_f(pv + 5, tbx);
        float cl1 = coord_loss(pv + 0, tbx);
        float cl2 = coord_loss(pv + 5, tbx);
        int c = (int)tv[0] - 1;
        float cls = 0.0f;
        #pragma unroll
        for (int k = 0; k < 20; ++k) {
            float d = pv[10 + k] - (k == c ? 1.0f : 0.0f);
            cls += d * d;
        }
        float d1 = c1 - iou1, d2 = c2 - iou2;
        loss = d1 * d1 + d2 * d2 + L_COORD * (cl1 + cl2) + cls;
    } else {
        loss = L_NOOBJ * (c1 * c1 + c2 * c2);
    }
    float local = loss * INV_BATCH;

    // ---- wave-64 reduce ----
    #pragma unroll
    for (int off = 32; off > 0; off >>= 1)
        local += __shfl_down(local, off);

    // ---- block reduce ----
    __shared__ float wsum[4];
    int lane = tid & 63;
    int wid = tid >> 6;
    if (lane == 0) wsum[wid] = local;
    __syncthreads();
    if (tid == 0) {
        float s = wsum[0] + wsum[1] + wsum[2] + wsum[3];
        atomicAdd(out, s);
    }
}

extern "C" void kernel_launch(void* const* d_in, const int* in_sizes, int n_in,
                              void* d_out, int out_size, void* d_ws, size_t ws_size,
                              hipStream_t stream) {
    const float* y_pre  = (const float*)d_in[0];
    const float* y_true = (const float*)d_in[1];
    float* out = (float*)d_out;

    hipMemsetAsync(out, 0, (size_t)out_size * sizeof(float), stream);
    yolo_loss_kernel<<<NBLOCKS, 256, 0, stream>>>(y_pre, y_true, out);
}

// Round 3
// 29.838 us; speedup vs baseline: 1.9957x; 1.9957x over previous
//
#include <hip/hip_runtime.h>

#define NCELLS (16384 * 7 * 7)   // 802816
#define NBLOCKS (NCELLS / 256)   // 3136, exact
#define INV_BATCH (1.0f / 16384.0f)
#define EPS 1e-12f
#define IMG 448.0f
#define CELL (448.0f / 7.0f)     // 64
#define L_COORD 5.0f
#define L_NOOBJ 0.5f

__device__ __forceinline__ float iou_f(const float* bp, const float* bt) {
    float cxp = bp[0] * CELL, cyp = bp[1] * CELL;
    float wp  = bp[2] * IMG,  hp  = bp[3] * IMG;
    float cxt = bt[0] * CELL, cyt = bt[1] * CELL;
    float wt  = bt[2] * IMG,  ht  = bt[3] * IMG;
    float iw = fmaxf(fminf(cxp + wp * 0.5f, cxt + wt * 0.5f) -
                     fmaxf(cxp - wp * 0.5f, cxt - wt * 0.5f), 0.0f);
    float ih = fmaxf(fminf(cyp + hp * 0.5f, cyt + ht * 0.5f) -
                     fmaxf(cyp - hp * 0.5f, cyt - ht * 0.5f), 0.0f);
    float inter = iw * ih;
    float uni = wp * hp + wt * ht - inter;
    return inter / (uni + EPS);
}

__device__ __forceinline__ float coord_loss(const float* bp, const float* tb) {
    float xy = (bp[0] - tb[0]) * (bp[0] - tb[0]) + (bp[1] - tb[1]) * (bp[1] - tb[1]);
    float s2 = sqrtf(bp[2] + EPS) - sqrtf(tb[2] + EPS);
    float s3 = sqrtf(bp[3] + EPS) - sqrtf(tb[3] + EPS);
    return xy + s2 * s2 + s3 * s3;
}

// Kernel 1: one cell per thread, one partial sum per block -> d_ws (NO atomics)
__global__ void __launch_bounds__(256) yolo_partial_kernel(
        const float* __restrict__ y_pre,
        const float* __restrict__ y_true,
        float* __restrict__ partial) {
    int idx = blockIdx.x * blockDim.x + threadIdx.x;

    // ---- y_pre: 30 floats, base 8B-aligned -> 15x float2 (independent, MLP) ----
    float pv[30];
    const float2* p2 = reinterpret_cast<const float2*>(y_pre + (size_t)idx * 30);
    #pragma unroll
    for (int i = 0; i < 15; ++i) {
        float2 v = p2[i];
        pv[2 * i]     = v.x;
        pv[2 * i + 1] = v.y;
    }
    // ---- y_true: 8 floats, 32B-aligned -> 2x float4 ----
    float tv[8];
    const float4* t4 = reinterpret_cast<const float4*>(y_true) + (size_t)idx * 2;
    float4 ta = t4[0], tb4 = t4[1];
    tv[0] = ta.x; tv[1] = ta.y; tv[2] = ta.z; tv[3] = ta.w;
    tv[4] = tb4.x; tv[5] = tb4.y; tv[6] = tb4.z; tv[7] = tb4.w;

    float c1 = pv[4], c2 = pv[9];
    bool obj = (tv[0] != 0.0f);
    float loss;
    if (obj) {
        const float* tbx = tv + 1;
        float iou1 = iou_f(pv + 0, tbx);
        float iou2 = iou_f(pv + 5, tbx);
        float cl1 = coord_loss(pv + 0, tbx);
        float cl2 = coord_loss(pv + 5, tbx);
        int c = (int)tv[0] - 1;
        float cls = 0.0f;
        #pragma unroll
        for (int k = 0; k < 20; ++k) {
            float d = pv[10 + k] - (k == c ? 1.0f : 0.0f);
            cls += d * d;
        }
        float d1 = c1 - iou1, d2 = c2 - iou2;
        loss = d1 * d1 + d2 * d2 + L_COORD * (cl1 + cl2) + cls;
    } else {
        loss = L_NOOBJ * (c1 * c1 + c2 * c2);
    }
    float local = loss * INV_BATCH;

    // ---- wave-64 reduce ----
    #pragma unroll
    for (int off = 32; off > 0; off >>= 1)
        local += __shfl_down(local, off);

    // ---- block reduce -> ONE plain store per block ----
    __shared__ float wsum[4];
    int lane = threadIdx.x & 63;
    int wid = threadIdx.x >> 6;
    if (lane == 0) wsum[wid] = local;
    __syncthreads();
    if (threadIdx.x == 0)
        partial[blockIdx.x] = wsum[0] + wsum[1] + wsum[2] + wsum[3];
}

// Kernel 2: single block sums the 3136 partials (L2-resident) -> out[0]
__global__ void __launch_bounds__(256) yolo_final_kernel(
        const float* __restrict__ partial,
        float* __restrict__ out) {
    float local = 0.0f;
    for (int i = threadIdx.x; i < NBLOCKS; i += 256)
        local += partial[i];

    #pragma unroll
    for (int off = 32; off > 0; off >>= 1)
        local += __shfl_down(local, off);

    __shared__ float wsum[4];
    int lane = threadIdx.x & 63;
    int wid = threadIdx.x >> 6;
    if (lane == 0) wsum[wid] = local;
    __syncthreads();
    if (threadIdx.x == 0)
        out[0] = wsum[0] + wsum[1] + wsum[2] + wsum[3];
}

extern "C" void kernel_launch(void* const* d_in, const int* in_sizes, int n_in,
                              void* d_out, int out_size, void* d_ws, size_t ws_size,
                              hipStream_t stream) {
    const float* y_pre  = (const float*)d_in[0];
    const float* y_true = (const float*)d_in[1];
    float* out = (float*)d_out;
    float* partial = (float*)d_ws;   // 3136 * 4 B = 12.5 KB

    yolo_partial_kernel<<<NBLOCKS, 256, 0, stream>>>(y_pre, y_true, partial);
    yolo_final_kernel<<<1, 256, 0, stream>>>(partial, out);
}